// Round 1
// baseline (664.253 us; speedup 1.0000x reference)
//
#include <hip/hip_runtime.h>

// GaussianSmoother: out[b,n] = sum_t x[b,t,n] * w[t],  w = normalized Gaussian(T=2048, sigma=20)
// x: [B=64, T=2048, N=1024] f32  -> out: [B, N] f32
// HBM-read-bound: 512 MiB in, ~85 us roofline at 6.3 TB/s.

#define B_DIM 64
#define T_DIM 2048
#define N_DIM 1024
#define SIGMA 20.0f

#define TC 8                    // T-chunks per block (reduced in LDS)
#define TSTEPS (T_DIM / TC)     // 256 t-steps per thread
#define NV 32                   // float4 lanes per block -> 128 n per block
#define BLOCK 256               // NV * TC

__global__ __launch_bounds__(BLOCK) void GaussianSmoother_kernel(
    const float* __restrict__ x, float* __restrict__ out) {
  __shared__ float w[T_DIM];            // 8 KiB Gaussian weights
  __shared__ float4 part[TC][NV];       // 4 KiB chunk partials
  __shared__ float wavesum[BLOCK / 64];
  __shared__ float inv_sum;

  const int tid = threadIdx.x;

  // ---- build (unnormalized) Gaussian weights in LDS, accumulate local sum ----
  float local = 0.0f;
#pragma unroll
  for (int i = tid; i < T_DIM; i += BLOCK) {
    float d = (float)(i - T_DIM / 2) * (1.0f / SIGMA);
    float e = expf(-0.5f * d * d);
    w[i] = e;
    local += e;
  }
  // wave(64)-level reduce, then cross-wave via LDS
#pragma unroll
  for (int off = 32; off > 0; off >>= 1) local += __shfl_down(local, off);
  if ((tid & 63) == 0) wavesum[tid >> 6] = local;
  __syncthreads();
  if (tid == 0) {
    float s = 0.0f;
#pragma unroll
    for (int i = 0; i < BLOCK / 64; ++i) s += wavesum[i];
    inv_sum = 1.0f / s;  // apply normalization once at the end
  }
  __syncthreads();

  // ---- main streaming reduction ----
  // thread -> (chunk of T, group of 4 consecutive n); block -> (b, 128-wide n-group)
  const int n4 = tid & (NV - 1);   // 0..31
  const int chunk = tid >> 5;      // 0..7
  const int b = blockIdx.x >> 3;   // 0..63
  const int ng = blockIdx.x & 7;   // 0..7

  const float4* px = (const float4*)x +
      ((size_t)b * T_DIM + (size_t)chunk * TSTEPS) * (N_DIM / 4) +
      (size_t)(ng * NV + n4);
  const float* wp = &w[chunk * TSTEPS];

  float4 acc = make_float4(0.0f, 0.0f, 0.0f, 0.0f);
#pragma unroll 8
  for (int i = 0; i < TSTEPS; ++i) {
    float4 v = px[(size_t)i * (N_DIM / 4)];
    float wt = wp[i];
    acc.x += wt * v.x;
    acc.y += wt * v.y;
    acc.z += wt * v.z;
    acc.w += wt * v.w;
  }
  part[chunk][n4] = acc;
  __syncthreads();

  // ---- reduce the TC partials, normalize, store ----
  if (tid < NV) {
    float4 s = part[0][tid];
#pragma unroll
    for (int c = 1; c < TC; ++c) {
      float4 p = part[c][tid];
      s.x += p.x; s.y += p.y; s.z += p.z; s.w += p.w;
    }
    const float inv = inv_sum;
    s.x *= inv; s.y *= inv; s.z *= inv; s.w *= inv;
    ((float4*)out)[(size_t)b * (N_DIM / 4) + (size_t)(ng * NV + tid)] = s;
  }
}

extern "C" void kernel_launch(void* const* d_in, const int* in_sizes, int n_in,
                              void* d_out, int out_size, void* d_ws, size_t ws_size,
                              hipStream_t stream) {
  const float* x = (const float*)d_in[0];
  float* out = (float*)d_out;
  // grid: 64 batches x 8 n-groups of 128 = 512 blocks (2 blocks/CU, 8 waves/CU)
  dim3 grid(B_DIM * (N_DIM / (NV * 4)));
  GaussianSmoother_kernel<<<grid, BLOCK, 0, stream>>>(x, out);
}